// Round 6
// baseline (1664.145 us; speedup 1.0000x reference)
//
#include <hip/hip_runtime.h>

// Problem constants (match reference)
#define NHEAD   16
#define DK      64
#define DMODEL  1024
#define BSZ     2
#define SEQLEN  1024
#define NI      64
#define NN2     1088          // SEQLEN + NI
#define NBUCK   9             // N_B + 1
#define TOPK    16

#define T_ITEM  (BSZ*SEQLEN)  // 2048 item tokens
#define T_INT   (BSZ*NN2)     // 2176 intent tokens

// workspace layout (bytes). total ~26.4 MB
#define Q_OFF   ((size_t)0)                          // q: 2048x1024 f32
#define K_OFF   (Q_OFF + (size_t)T_ITEM*DMODEL*4)    // k: 2176x1024 f32
#define V_OFF   (K_OFF + (size_t)T_INT*DMODEL*4)     // v: 2176x1024 f32
#define CNT_OFF (V_OFF + (size_t)T_INT*DMODEL*4)     // counts: 18 ints
#define LI_OFF  (CNT_OFF + 128)                      // item lists 9x2048
#define LN_OFF  (LI_OFF + (size_t)NBUCK*T_ITEM*4)    // intent lists 9x2176
#define WS_NEED (LN_OFF + (size_t)NBUCK*T_INT*4)

// fp64 sidecar buffers live INSIDE the V region (used before v-GEMM writes it):
//   q0d: 2048*64 f64 (1 MB), k0d: 2176*64 f64 (1.1 MB)  — V region is 8.9 MB.
#define Q0D_OFF V_OFF
#define K0D_OFF (V_OFF + (size_t)T_ITEM*64*8)

#define X_OUT_ELEMS ((size_t)BSZ*SEQLEN*DMODEL)      // 2,097,152
#define SIDX_ELEMS  ((size_t)BSZ*SEQLEN)             // 2048

__device__ __forceinline__ int clampi(int v, int lo, int hi) {
  return v < lo ? lo : (v > hi ? hi : v);
}

// ---------------------------------------------------------------------------
// Kernel 1: counting-sort tokens into buckets (order within bucket irrelevant)
// ---------------------------------------------------------------------------
__global__ void bucketize_kernel(const int* __restrict__ b_seq, const int* __restrict__ b_seq2,
                                 int* __restrict__ cnt, int* __restrict__ list_item,
                                 int* __restrict__ list_int) {
  int t = blockIdx.x * blockDim.x + threadIdx.x;
  if (t < T_ITEM) {
    int B = clampi(b_seq[t], 0, NBUCK - 1);
    int p = atomicAdd(&cnt[B], 1);
    if (p >= 0 && p < T_ITEM) list_item[B * T_ITEM + p] = t;
  }
  if (t < T_INT) {
    int B = clampi(b_seq2[t], 0, NBUCK - 1);
    int p = atomicAdd(&cnt[NBUCK + B], 1);
    if (p >= 0 && p < T_INT) list_int[B * T_INT + p] = t;
  }
}

// ---------------------------------------------------------------------------
// fp64 sidecar A: head-0 projection  Y[tok][k] = sum_d X[tok][d]*W[B][d][k]
// (k = 0..63 = head 0 columns). One wave per token; lane = k. Reads b_seq
// directly — independent of the bucketize/list path.
// ---------------------------------------------------------------------------
__global__ __launch_bounds__(256) void proj_head0_f64(
    const float* __restrict__ X, const float* __restrict__ W,
    const int* __restrict__ bseq, double* __restrict__ Y, const int T) {
  const int wave = (int)threadIdx.x >> 6, lane = (int)threadIdx.x & 63;
  const int tok = blockIdx.x * 4 + wave;
  if (tok >= T) return;
  const int B = clampi(bseq[tok], 0, NBUCK - 1);
  const float* xr = X + (size_t)tok * DMODEL;
  const float* wb = W + (size_t)B * DMODEL * (NHEAD * DK) + lane;  // W[B][d][lane]
  double acc = 0.0;
  #pragma unroll 4
  for (int d = 0; d < DMODEL; ++d)
    acc += (double)xr[d] * (double)wb[(size_t)d * (NHEAD * DK)];
  Y[(size_t)tok * 64 + lane] = acc;
}

// ---------------------------------------------------------------------------
// fp64 sidecar B: per q-row fp64 scores over all 1088 keys; exact
// first-occurrence argmax over [0,1024) -> sIdx and [1024,1088) -> aIdx.
// softmax is monotone -> argmax(p) == argmax(scores); /sqrt(64) scaling
// does not affect ordering. One block (256 thr) per q-row.
// ---------------------------------------------------------------------------
__global__ __launch_bounds__(256) void argmax_f64(
    const double* __restrict__ Q0, const double* __restrict__ K0,
    float* __restrict__ out_s, float* __restrict__ out_a) {
  const int n = blockIdx.x;          // b*1024 + nn
  const int b = n >> 10;
  const int t = (int)threadIdx.x;
  __shared__ double qs[64];
  __shared__ double bval[256];  __shared__ int bidx[256];
  __shared__ double bval2[256]; __shared__ int bidx2[256];
  if (t < 64) qs[t] = Q0[(size_t)n * 64 + t];
  __syncthreads();
  double v1 = -1e300; int i1 = 0x7FFFFFFF;
  double v2 = -1e300; int i2 = 0x7FFFFFFF;
  for (int m = t; m < NN2; m += 256) {
    const double* kr = K0 + (size_t)(b * NN2 + m) * 64;
    double s = 0.0;
    #pragma unroll 8
    for (int k = 0; k < 64; ++k) s += qs[k] * kr[k];
    if (m < 1024) { if (s > v1 || (s == v1 && m < i1)) { v1 = s; i1 = m; } }
    else          { if (s > v2 || (s == v2 && m < i2)) { v2 = s; i2 = m; } }
  }
  bval[t] = v1; bidx[t] = i1; bval2[t] = v2; bidx2[t] = i2;
  __syncthreads();
  for (int off = 128; off >= 1; off >>= 1) {
    if (t < off) {
      if (bval[t+off] >  bval[t] || (bval[t+off] ==  bval[t] &&  bidx[t+off] <  bidx[t])) { bval[t]  = bval[t+off];  bidx[t]  = bidx[t+off]; }
      if (bval2[t+off] > bval2[t] || (bval2[t+off] == bval2[t] && bidx2[t+off] < bidx2[t])) { bval2[t] = bval2[t+off]; bidx2[t] = bidx2[t+off]; }
    }
    __syncthreads();
  }
  if (t == 0) {
    out_s[n] = (float)bidx[0];
    out_a[n] = (float)(bidx2[0] - 1024);
  }
}

// ---------------------------------------------------------------------------
// Kernel 2: grouped GEMM  Y[tok] = X[tok] @ W[bucket(tok)]  (fp32)
// tile 128x128, BK=16, 256 threads, 8x8 micro-tile per thread
// ---------------------------------------------------------------------------
#define TM  128
#define TN  128
#define GBK 16

__global__ __launch_bounds__(256) void gemm_grouped(
    const float* __restrict__ X, const float* __restrict__ W,
    const int* __restrict__ list, const int* __restrict__ cnt,
    float* __restrict__ Y, const int Tmax) {
  const int B = blockIdx.z;
  const int n = min(cnt[B], Tmax);       // defensive clamp
  const int row0 = blockIdx.y * TM;
  if (row0 >= n) return;                 // uniform across block: no divergent barrier
  const int rows = min(TM, n - row0);
  const int c0 = blockIdx.x * TN;
  const int t = (int)threadIdx.x;

  __shared__ float Xs[GBK][TM + 4];   // k-major (transposed on store)
  __shared__ float Ws[GBK][TN + 4];

  const int tokA = t >> 1;            // 0..127
  const int kqA  = (t & 1) * 8;       // 0 or 8
  const int liA  = clampi(list[row0 + min(tokA, rows - 1)], 0, Tmax - 1);
  const float* xrow = X + (size_t)liA * DMODEL;
  const int kW = t >> 4;              // 0..15
  const int cW = (t & 15) * 8;        // 0..120

  const int ty = t >> 4;              // row group (8 rows)
  const int tx = t & 15;              // col group (8 cols)

  float acc[8][8];
  #pragma unroll
  for (int i = 0; i < 8; ++i)
    #pragma unroll
    for (int j = 0; j < 8; ++j) acc[i][j] = 0.f;

  for (int k0 = 0; k0 < DMODEL; k0 += GBK) {
    float4 xa = *(const float4*)(xrow + k0 + kqA);
    float4 xb = *(const float4*)(xrow + k0 + kqA + 4);
    const float* wp = W + ((size_t)B * DMODEL + k0 + kW) * (size_t)(NHEAD * DK) + c0 + cW;
    float4 wa = *(const float4*)wp;
    float4 wb = *(const float4*)(wp + 4);

    Xs[kqA + 0][tokA] = xa.x; Xs[kqA + 1][tokA] = xa.y;
    Xs[kqA + 2][tokA] = xa.z; Xs[kqA + 3][tokA] = xa.w;
    Xs[kqA + 4][tokA] = xb.x; Xs[kqA + 5][tokA] = xb.y;
    Xs[kqA + 6][tokA] = xb.z; Xs[kqA + 7][tokA] = xb.w;
    *(float4*)&Ws[kW][cW]     = wa;
    *(float4*)&Ws[kW][cW + 4] = wb;
    __syncthreads();

    #pragma unroll
    for (int kk = 0; kk < GBK; ++kk) {
      float a[8], bv[8];
      *(float4*)&a[0]  = *(const float4*)&Xs[kk][ty * 8];
      *(float4*)&a[4]  = *(const float4*)&Xs[kk][ty * 8 + 4];
      *(float4*)&bv[0] = *(const float4*)&Ws[kk][tx * 8];
      *(float4*)&bv[4] = *(const float4*)&Ws[kk][tx * 8 + 4];
      #pragma unroll
      for (int i = 0; i < 8; ++i)
        #pragma unroll
        for (int j = 0; j < 8; ++j)
          acc[i][j] = fmaf(a[i], bv[j], acc[i][j]);
    }
    __syncthreads();
  }

  #pragma unroll
  for (int i = 0; i < 8; ++i) {
    const int r = ty * 8 + i;
    if (r < rows) {
      const int tok = clampi(list[row0 + r], 0, Tmax - 1);
      float* yr = Y + (size_t)tok * (size_t)(NHEAD * DK) + c0 + tx * 8;
      float4 o0 = make_float4(acc[i][0], acc[i][1], acc[i][2], acc[i][3]);
      float4 o1 = make_float4(acc[i][4], acc[i][5], acc[i][6], acc[i][7]);
      *(float4*)yr       = o0;
      *(float4*)(yr + 4) = o1;
    }
  }
}

// ---------------------------------------------------------------------------
// Kernel 3: fused attention: scores -> softmax -> exact top-16 per segment ->
//           sparse p@V.  (index outputs come from the fp64 sidecar)
// Block = 256 thr (4 waves), 16 q-rows per block (4 per wave).
// ---------------------------------------------------------------------------
__device__ __forceinline__ float readlane_f(float v, int l) {
  return __int_as_float(__builtin_amdgcn_readlane(__float_as_int(v), l));
}

__global__ __launch_bounds__(256) void attn_kernel(
    const float* __restrict__ Q, const float* __restrict__ K,
    const float* __restrict__ V, float* __restrict__ outx) {
  const int b = blockIdx.z, h = blockIdx.y;
  const int n0 = blockIdx.x * 16;
  const int t = (int)threadIdx.x;
  const int wave = t >> 6, lane = t & 63;

  __shared__ float Qs[16][64];
  __shared__ float Ks[64][68];        // +4 pad: conflict-free b128
  __shared__ int   kept_m[16][32];
  __shared__ float kept_p[16][32];

  {
    const int r = t >> 4, k4 = (t & 15) * 4;
    *(float4*)&Qs[r][k4] =
        *(const float4*)(Q + (size_t)(b * SEQLEN + n0 + r) * (NHEAD * DK) + h * DK + k4);
  }
  __syncthreads();

  const float qr0 = Qs[wave * 4 + 0][lane];
  const float qr1 = Qs[wave * 4 + 1][lane];
  const float qr2 = Qs[wave * 4 + 2][lane];
  const float qr3 = Qs[wave * 4 + 3][lane];

  float s0[17], s1[17], s2[17], s3[17];   // score at m = c*64 + lane

  #pragma unroll
  for (int c = 0; c < 17; ++c) {
    if (c > 0) __syncthreads();
    #pragma unroll
    for (int j = 0; j < 4; ++j) {
      const int row = (t >> 4) + 16 * j;
      const int k4 = (t & 15) * 4;
      *(float4*)&Ks[row][k4] =
          *(const float4*)(K + (size_t)(b * NN2 + c * 64 + row) * (NHEAD * DK) + h * DK + k4);
    }
    __syncthreads();

    float a0 = 0.f, a1 = 0.f, a2 = 0.f, a3 = 0.f;
    #pragma unroll 4
    for (int k4 = 0; k4 < 64; k4 += 4) {
      const float4 kv = *(const float4*)&Ks[lane][k4];
      #pragma unroll
      for (int u = 0; u < 4; ++u) {
        const float kvu = (u == 0) ? kv.x : (u == 1) ? kv.y : (u == 2) ? kv.z : kv.w;
        a0 = fmaf(readlane_f(qr0, k4 + u), kvu, a0);
        a1 = fmaf(readlane_f(qr1, k4 + u), kvu, a1);
        a2 = fmaf(readlane_f(qr2, k4 + u), kvu, a2);
        a3 = fmaf(readlane_f(qr3, k4 + u), kvu, a3);
      }
    }
    s0[c] = a0 * 0.125f; s1[c] = a1 * 0.125f;
    s2[c] = a2 * 0.125f; s3[c] = a3 * 0.125f;
  }

  auto process_row = [&](const float (&sv)[17], const int rr) {
    const int r_loc = wave * 4 + rr;
    float M = -3.402823466e38f;
    #pragma unroll
    for (int c = 0; c < 17; ++c) M = fmaxf(M, sv[c]);
    #pragma unroll
    for (int off = 32; off >= 1; off >>= 1) M = fmaxf(M, __shfl_xor(M, off));
    float L = 0.f;
    #pragma unroll
    for (int c = 0; c < 17; ++c) L += __expf(sv[c] - M);
    #pragma unroll
    for (int off = 32; off >= 1; off >>= 1) L += __shfl_xor(L, off);
    const float invL = 1.0f / L;

    // segment 1: top-16 of m in [0,1024)
    unsigned msk = 0xFFFFu;
    for (int round = 0; round < TOPK; ++round) {
      float bv = -3.402823466e38f; int bc = -1;
      #pragma unroll
      for (int c = 0; c < 16; ++c) {
        const bool ok = (msk >> c) & 1u;
        const float v = sv[c];
        if (ok && v > bv) { bv = v; bc = c; }
      }
      int bm = (bc >= 0) ? (bc * 64 + lane) : 0x3FFFFFFF;
      #pragma unroll
      for (int off = 1; off < 64; off <<= 1) {
        const float ov = __shfl_xor(bv, off);
        const int   om = __shfl_xor(bm, off);
        if (ov > bv || (ov == bv && om < bm)) { bv = ov; bm = om; }
      }
      if (bm < 1024 && (bm & 63) == lane) msk &= ~(1u << (bm >> 6));
      if (lane == round) { kept_m[r_loc][round] = bm; kept_p[r_loc][round] = __expf(bv - M) * invL; }
    }

    // segment 2: top-16 of the NI=64 tail
    const float v2 = sv[16];
    bool act = true;
    for (int round = 0; round < TOPK; ++round) {
      float bv = act ? v2 : -3.402823466e38f;
      int   bm = act ? lane : 0x3FFFFFFF;
      #pragma unroll
      for (int off = 1; off < 64; off <<= 1) {
        const float ov = __shfl_xor(bv, off);
        const int   om = __shfl_xor(bm, off);
        if (ov > bv || (ov == bv && om < bm)) { bv = ov; bm = om; }
      }
      if (bm == lane) act = false;
      if (lane == round) {
        kept_m[r_loc][TOPK + round] = 1024 + (bm & 63);
        kept_p[r_loc][TOPK + round] = __expf(bv - M) * invL;
      }
    }
  };
  process_row(s0, 0); process_row(s1, 1); process_row(s2, 2); process_row(s3, 3);
  __syncthreads();

  #pragma unroll
  for (int rr = 0; rr < 4; ++rr) {
    const int r_loc = wave * 4 + rr;
    const int n = n0 + r_loc;
    float x = 0.f;
    #pragma unroll
    for (int i = 0; i < 32; ++i) {
      const int m = clampi(kept_m[r_loc][i], 0, NN2 - 1);
      const float p = kept_p[r_loc][i];
      x = fmaf(p, V[(size_t)(b * NN2 + m) * (NHEAD * DK) + h * DK + lane], x);
    }
    outx[(size_t)(b * SEQLEN + n) * (NHEAD * DK) + h * DK + lane] = x;
  }
}

// ---------------------------------------------------------------------------
extern "C" void kernel_launch(void* const* d_in, const int* in_sizes, int n_in,
                              void* d_out, int out_size, void* d_ws, size_t ws_size,
                              hipStream_t stream) {
  const float* item    = (const float*)d_in[0];
  const float* intent  = (const float*)d_in[1];
  // d_in[2] = mask: constant all-True -> no-op, skipped
  const int*   b_seq   = (const int*)d_in[3];
  const int*   b_seq2  = (const int*)d_in[4];
  const float* W_item  = (const float*)d_in[5];   // [9][1024][16][64]
  const float* W_int   = (const float*)d_in[6];   // [2][9][1024][16][64]

  if (ws_size < WS_NEED) return;   // clean failure instead of device fault

  char* ws = (char*)d_ws;
  float* qb = (float*)(ws + Q_OFF);
  float* kb = (float*)(ws + K_OFF);
  float* vb = (float*)(ws + V_OFF);
  double* q0d = (double*)(ws + Q0D_OFF);   // aliases V region (used before v-GEMM)
  double* k0d = (double*)(ws + K0D_OFF);
  int* cnt       = (int*)(ws + CNT_OFF);
  int* list_item = (int*)(ws + LI_OFF);
  int* list_int  = (int*)(ws + LN_OFF);

  float* outx  = (float*)d_out;
  float* out_s = outx + X_OUT_ELEMS;
  float* out_a = out_s + SIDX_ELEMS;

  hipMemsetAsync(cnt, 0, 128, stream);
  bucketize_kernel<<<dim3(9), 256, 0, stream>>>(b_seq, b_seq2, cnt, list_item, list_int);

  // fp64 sidecar: head-0 q/k projections + exact argmax -> sIdx, aIdx.
  // Uses the V workspace region BEFORE the v-GEMM overwrites it.
  proj_head0_f64<<<dim3((T_ITEM + 3) / 4), 256, 0, stream>>>(item, W_item, b_seq, q0d, T_ITEM);
  proj_head0_f64<<<dim3((T_INT + 3) / 4), 256, 0, stream>>>(intent, W_int, b_seq2, k0d, T_INT);
  argmax_f64<<<dim3(T_ITEM), 256, 0, stream>>>(q0d, k0d, out_s, out_a);

  // fp32 pipeline for x
  gemm_grouped<<<dim3(8, 16, 9), 256, 0, stream>>>(item, W_item, list_item, cnt, qb, T_ITEM);
  gemm_grouped<<<dim3(8, 17, 9), 256, 0, stream>>>(intent, W_int, list_int, cnt + NBUCK, kb, T_INT);
  gemm_grouped<<<dim3(8, 17, 9), 256, 0, stream>>>(intent, W_int + (size_t)NBUCK * DMODEL * (NHEAD * DK),
                                                   list_int, cnt + NBUCK, vb, T_INT);

  attn_kernel<<<dim3(SEQLEN / 16, NHEAD, BSZ), 256, 0, stream>>>(qb, kb, vb, outx);
}